// Round 1
// baseline (1731.203 us; speedup 1.0000x reference)
//
#include <hip/hip_runtime.h>

#define NPOSTS 2048
#define SEQ 64
#define W2V 300
#define NH 5
#define HD 60
#define S2VD 256
#define HIDD 256
#define NEDGE 2047

// ---------------- Stage 1: fused embed-gather + MHA(query 0) + tanh(s2v) ----------------
__global__ __launch_bounds__(256) void k_mha_s2v(
    const int* __restrict__ nodeText, const float* __restrict__ embed_w,
    const float* __restrict__ Wqkv, const float* __restrict__ bqkv,
    const float* __restrict__ Wo, const float* __restrict__ bo,
    const float* __restrict__ Ws, const float* __restrict__ bs,
    float* __restrict__ s2v_out)
{
    __shared__ float sEmb[SEQ][W2V + 1];   // stride 301: odd -> bank-conflict-free row reads
    __shared__ int   stoks[SEQ];
    __shared__ float sq[W2V];
    __shared__ float su[NH * W2V];
    __shared__ float ssc[NH * SEQ];
    __shared__ float sinv[NH];
    __shared__ float se[NH * W2V];
    __shared__ float so[W2V];
    __shared__ float smha[W2V];

    const int p = blockIdx.x;
    const int tid = threadIdx.x;

    if (tid < SEQ) stoks[tid] = nodeText[p * SEQ + tid];
    __syncthreads();

    // gather 64 embedding rows (float4 global loads, scalar LDS stores due to 301 stride)
    for (int idx = tid; idx < SEQ * 75; idx += 256) {
        int r = idx / 75, c4 = (idx % 75) * 4;
        const float4 v = *reinterpret_cast<const float4*>(embed_w + (size_t)stoks[r] * W2V + c4);
        float* dst = &sEmb[r][c4];
        dst[0] = v.x; dst[1] = v.y; dst[2] = v.z; dst[3] = v.w;
    }
    __syncthreads();

    // q = W_q @ Emb[0] + b_q   (300 outputs)
    for (int d = tid; d < W2V; d += 256) {
        const float* wr = Wqkv + (size_t)d * W2V;
        float acc = bqkv[d];
        #pragma unroll 4
        for (int c = 0; c < W2V; ++c) acc = fmaf(wr[c], sEmb[0][c], acc);
        sq[d] = acc;
    }
    __syncthreads();

    // u_h = W_k_h^T q_h  (5 x 300); k-bias constant cancels in softmax
    for (int idx = tid; idx < NH * W2V; idx += 256) {
        int h = idx / W2V, c = idx % W2V;
        const float* wb = Wqkv + (size_t)(W2V + h * HD) * W2V + c;
        const float* qh = sq + h * HD;
        float acc = 0.f;
        #pragma unroll 4
        for (int d = 0; d < HD; ++d) acc = fmaf(wb[d * W2V], qh[d], acc);
        su[idx] = acc;
    }
    __syncthreads();

    // scores[h][j] = (u_h . Emb[j]) / sqrt(60)
    for (int idx = tid; idx < NH * SEQ; idx += 256) {
        int h = idx / SEQ, j = idx % SEQ;
        const float* uh = su + h * W2V;
        const float* er = sEmb[j];
        float acc = 0.f;
        #pragma unroll 4
        for (int c = 0; c < W2V; ++c) acc = fmaf(uh[c], er[c], acc);
        ssc[idx] = acc * 0.12909944487358056f;  // 60^-0.5
    }
    __syncthreads();

    // softmax per head (5 serial threads; 64 elements each)
    if (tid < NH) {
        float m = -1e30f;
        for (int j = 0; j < SEQ; ++j) m = fmaxf(m, ssc[tid * SEQ + j]);
        float s = 0.f;
        for (int j = 0; j < SEQ; ++j) {
            float e = expf(ssc[tid * SEQ + j] - m);
            ssc[tid * SEQ + j] = e;
            s += e;
        }
        sinv[tid] = 1.f / s;
    }
    __syncthreads();

    // e_h = sum_j att[h,j] * Emb[j]  (5 x 300)
    for (int idx = tid; idx < NH * W2V; idx += 256) {
        int h = idx / W2V, c = idx % W2V;
        float acc = 0.f;
        #pragma unroll 4
        for (int j = 0; j < SEQ; ++j) acc = fmaf(ssc[h * SEQ + j], sEmb[j][c], acc);
        se[idx] = acc * sinv[h];
    }
    __syncthreads();

    // o = W_v_h @ e_h + b_v  (300)
    for (int d = tid; d < W2V; d += 256) {
        int h = d / HD;
        const float* wr = Wqkv + (size_t)(2 * W2V + d) * W2V;
        const float* eh = se + h * W2V;
        float acc = bqkv[2 * W2V + d];
        #pragma unroll 4
        for (int c = 0; c < W2V; ++c) acc = fmaf(wr[c], eh[c], acc);
        so[d] = acc;
    }
    __syncthreads();

    // mha0 = W_o @ o + b_o  (300)
    for (int d = tid; d < W2V; d += 256) {
        const float* wr = Wo + (size_t)d * W2V;
        float acc = bo[d];
        #pragma unroll 4
        for (int c = 0; c < W2V; ++c) acc = fmaf(wr[c], so[c], acc);
        smha[d] = acc;
    }
    __syncthreads();

    // s2v row = tanh(Ws @ mha0 + bs)  (256)
    {
        const float* wr = Ws + (size_t)tid * W2V;
        float acc = bs[tid];
        #pragma unroll 4
        for (int c = 0; c < W2V; ++c) acc = fmaf(wr[c], smha[c], acc);
        s2v_out[(size_t)p * S2VD + tid] = tanhf(acc);
    }
}

// ---------------- Stage 2: GCN branches (blockIdx.y = branch: 0=TD, 1=BU) ----------------

__global__ __launch_bounds__(256) void k_deg(
    const int* __restrict__ eiTD, const int* __restrict__ eiBU, int* __restrict__ deg)
{
    const int b = blockIdx.y;
    const int* ei = b ? eiBU : eiTD;
    int e = blockIdx.x * 256 + threadIdx.x;
    if (e < NEDGE) atomicAdd(&deg[b * NPOSTS + ei[NEDGE + e]], 1);
}

// h = x @ w.T  (K = 256, w row-major 256x256), 16 rows per WG
__global__ __launch_bounds__(256) void k_gemm1(
    const float* __restrict__ x, const float* __restrict__ wtd, const float* __restrict__ wbu,
    float* __restrict__ hout)
{
    const int b = blockIdx.y;
    const float* w = b ? wbu : wtd;
    float* outp = hout + (size_t)b * NPOSTS * HIDD;
    const int r0 = blockIdx.x * 16;
    const int tid = threadIdx.x;
    __shared__ float sx[16][S2VD];
    for (int i = tid; i < 16 * S2VD; i += 256)
        sx[i / S2VD][i % S2VD] = x[(size_t)(r0 + i / S2VD) * S2VD + (i % S2VD)];
    __syncthreads();
    float acc[16];
    #pragma unroll
    for (int r = 0; r < 16; ++r) acc[r] = 0.f;
    const float* wr = w + (size_t)tid * S2VD;
    for (int c = 0; c < S2VD; ++c) {
        float wv = wr[c];
        #pragma unroll
        for (int r = 0; r < 16; ++r) acc[r] = fmaf(wv, sx[r][c], acc[r]);
    }
    #pragma unroll
    for (int r = 0; r < 16; ++r) outp[(size_t)(r0 + r) * HIDD + tid] = acc[r];
}

// h2 = relu(c1) @ w2[:, :256].T + rootvec  (w2 row stride 512)
__global__ __launch_bounds__(256) void k_gemm2(
    const float* __restrict__ c1, const float* __restrict__ w2td, const float* __restrict__ w2bu,
    const float* __restrict__ rootv, float* __restrict__ hout)
{
    const int b = blockIdx.y;
    const float* w = b ? w2bu : w2td;
    const float* xin = c1 + (size_t)b * NPOSTS * HIDD;
    float* outp = hout + (size_t)b * NPOSTS * HIDD;
    const int r0 = blockIdx.x * 16;
    const int tid = threadIdx.x;
    __shared__ float sx[16][HIDD];
    for (int i = tid; i < 16 * HIDD; i += 256)
        sx[i / HIDD][i % HIDD] = fmaxf(xin[(size_t)(r0 + i / HIDD) * HIDD + (i % HIDD)], 0.f);
    __syncthreads();
    float acc[16];
    const float rv = rootv[b * HIDD + tid];
    #pragma unroll
    for (int r = 0; r < 16; ++r) acc[r] = rv;
    const float* wr = w + (size_t)tid * 512;
    for (int c = 0; c < HIDD; ++c) {
        float wv = wr[c];
        #pragma unroll
        for (int r = 0; r < 16; ++r) acc[r] = fmaf(wv, sx[r][c], acc[r]);
    }
    #pragma unroll
    for (int r = 0; r < 16; ++r) outp[(size_t)(r0 + r) * HIDD + tid] = acc[r];
}

// c[n] = bias + h[n] / (deg[n]+1)   (self-loop term + bias init)
__global__ __launch_bounds__(256) void k_init(
    const float* __restrict__ h, const float* __restrict__ btd, const float* __restrict__ bbu,
    const int* __restrict__ deg, float* __restrict__ cout_)
{
    const int b = blockIdx.y, n = blockIdx.x, tid = threadIdx.x;
    const float* bias = b ? bbu : btd;
    const float* hb = h + (size_t)b * NPOSTS * HIDD;
    float* cb = cout_ + (size_t)b * NPOSTS * HIDD;
    float dinv = 1.f / (float)(deg[b * NPOSTS + n] + 1);
    cb[(size_t)n * HIDD + tid] = bias[tid] + hb[(size_t)n * HIDD + tid] * dinv;
}

// scatter edges: c[dst] += norm * h[src]
__global__ __launch_bounds__(256) void k_scat(
    const int* __restrict__ eiTD, const int* __restrict__ eiBU,
    const float* __restrict__ h, const int* __restrict__ deg, float* __restrict__ cacc)
{
    const int b = blockIdx.y, e = blockIdx.x, tid = threadIdx.x;
    const int* ei = b ? eiBU : eiTD;
    const int s = ei[e], d = ei[NEDGE + e];
    const int* dg = deg + b * NPOSTS;
    float norm = rsqrtf((float)(dg[s] + 1)) * rsqrtf((float)(dg[d] + 1));
    const float* hb = h + (size_t)b * NPOSTS * HIDD;
    float* cb = cacc + (size_t)b * NPOSTS * HIDD;
    atomicAdd(&cb[(size_t)d * HIDD + tid], norm * hb[(size_t)s * HIDD + tid]);
}

// rootvec[j] = w2[j, 256:512] . relu(s2v[root]);  also copy raw c1[root]
__global__ __launch_bounds__(256) void k_root(
    const float* __restrict__ s2v, const float* __restrict__ c1,
    const float* __restrict__ w2td, const float* __restrict__ w2bu,
    const int* __restrict__ rootPtr, float* __restrict__ rootv, float* __restrict__ c1root)
{
    const int b = blockIdx.y, tid = threadIdx.x;
    const float* w2 = b ? w2bu : w2td;
    const int root = rootPtr[0];
    __shared__ float sx[S2VD];
    sx[tid] = fmaxf(s2v[(size_t)root * S2VD + tid], 0.f);
    __syncthreads();
    const float* cb = c1 + (size_t)b * NPOSTS * HIDD;
    c1root[b * HIDD + tid] = cb[(size_t)root * HIDD + tid];
    const float* wr = w2 + (size_t)tid * 512 + 256;
    float acc = 0.f;
    #pragma unroll 4
    for (int c = 0; c < S2VD; ++c) acc = fmaf(wr[c], sx[c], acc);
    rootv[b * HIDD + tid] = acc;
}

// msum[b] += sum over 32 rows of relu(c2acc)
__global__ __launch_bounds__(256) void k_reduce(
    const float* __restrict__ cacc, float* __restrict__ msum)
{
    const int b = blockIdx.y, tid = threadIdx.x;
    const int base = blockIdx.x * 32;
    const float* cb = cacc + (size_t)b * NPOSTS * HIDD;
    float local = 0.f;
    #pragma unroll 4
    for (int r = 0; r < 32; ++r) local += fmaxf(cb[(size_t)(base + r) * HIDD + tid], 0.f);
    atomicAdd(&msum[b * HIDD + tid], local);
}

// out[t] = fc_b[t] + fc_w[t] . [c1root_td, mean_td, c1root_bu, mean_bu]
__global__ __launch_bounds__(256) void k_final(
    const float* __restrict__ c1root, const float* __restrict__ msum,
    const float* __restrict__ fc_w, const float* __restrict__ fc_b, float* __restrict__ outp)
{
    const int tid = threadIdx.x;
    __shared__ float sf[1024];
    for (int k = tid; k < 1024; k += 256) {
        int seg = k >> 8, idx = k & 255;
        float v;
        if (seg == 0)      v = c1root[idx];
        else if (seg == 1) v = msum[idx] * (1.f / (float)NPOSTS);
        else if (seg == 2) v = c1root[256 + idx];
        else               v = msum[256 + idx] * (1.f / (float)NPOSTS);
        sf[k] = v;
    }
    __syncthreads();
    const int t = tid >> 6, lane = tid & 63;
    float part = 0.f;
    for (int k = lane; k < 1024; k += 64) part = fmaf(fc_w[t * 1024 + k], sf[k], part);
    #pragma unroll
    for (int off = 32; off > 0; off >>= 1) part += __shfl_down(part, off);
    if (lane == 0) outp[t] = part + fc_b[t];
}

extern "C" void kernel_launch(void* const* d_in, const int* in_sizes, int n_in,
                              void* d_out, int out_size, void* d_ws, size_t ws_size,
                              hipStream_t stream) {
    (void)in_sizes; (void)n_in; (void)out_size; (void)ws_size;

    const int*   nodeText   = (const int*)d_in[0];
    const int*   eiTD       = (const int*)d_in[1];
    const int*   eiBU       = (const int*)d_in[2];
    const int*   threadIdxP = (const int*)d_in[3];
    // d_in[4] = mission (unused by reference)
    const float* embed_w    = (const float*)d_in[5];
    const float* in_proj_w  = (const float*)d_in[6];
    const float* in_proj_b  = (const float*)d_in[7];
    const float* out_proj_w = (const float*)d_in[8];
    const float* out_proj_b = (const float*)d_in[9];
    const float* s2v_w      = (const float*)d_in[10];
    const float* s2v_b      = (const float*)d_in[11];
    const float* td_w1      = (const float*)d_in[12];
    const float* td_b1      = (const float*)d_in[13];
    const float* td_w2      = (const float*)d_in[14];
    const float* td_b2      = (const float*)d_in[15];
    const float* bu_w1      = (const float*)d_in[16];
    const float* bu_b1      = (const float*)d_in[17];
    const float* bu_w2      = (const float*)d_in[18];
    const float* bu_b2      = (const float*)d_in[19];
    const float* fc_w       = (const float*)d_in[20];
    const float* fc_b       = (const float*)d_in[21];
    float* outp = (float*)d_out;

    // workspace layout
    char* w = (char*)d_ws;
    int*   deg    = (int*)w;                          // 2*2048 ints    (16384 B)
    float* msum   = (float*)(w + 16384);              // 2*256 floats   (2048 B)
    float* rootv  = (float*)(w + 16384 + 2048);       // 2*256 floats
    float* c1root = (float*)(w + 16384 + 4096);       // 2*256 floats
    float* s2v    = (float*)(w + 24576);                              // 2 MB
    float* hbuf   = (float*)(w + 24576 + 2097152);                    // 4 MB (h1 then h2)
    float* cbuf   = (float*)(w + 24576 + 2097152 + 4194304);          // 4 MB (c1 then c2)

    // zero deg + msum (accumulators) each call
    hipMemsetAsync(d_ws, 0, 16384 + 2048, stream);

    k_mha_s2v<<<NPOSTS, 256, 0, stream>>>(nodeText, embed_w, in_proj_w, in_proj_b,
                                          out_proj_w, out_proj_b, s2v_w, s2v_b, s2v);

    k_deg<<<dim3((NEDGE + 255) / 256, 2), 256, 0, stream>>>(eiTD, eiBU, deg);

    k_gemm1<<<dim3(NPOSTS / 16, 2), 256, 0, stream>>>(s2v, td_w1, bu_w1, hbuf);
    k_init<<<dim3(NPOSTS, 2), 256, 0, stream>>>(hbuf, td_b1, bu_b1, deg, cbuf);
    k_scat<<<dim3(NEDGE, 2), 256, 0, stream>>>(eiTD, eiBU, hbuf, deg, cbuf);

    k_root<<<dim3(1, 2), 256, 0, stream>>>(s2v, cbuf, td_w2, bu_w2, threadIdxP, rootv, c1root);

    k_gemm2<<<dim3(NPOSTS / 16, 2), 256, 0, stream>>>(cbuf, td_w2, bu_w2, rootv, hbuf);
    k_init<<<dim3(NPOSTS, 2), 256, 0, stream>>>(hbuf, td_b2, bu_b2, deg, cbuf);
    k_scat<<<dim3(NEDGE, 2), 256, 0, stream>>>(eiTD, eiBU, hbuf, deg, cbuf);

    k_reduce<<<dim3(NPOSTS / 32, 2), 256, 0, stream>>>(cbuf, msum);

    k_final<<<1, 256, 0, stream>>>(c1root, msum, fc_w, fc_b, outp);
}

// Round 2
// 345.318 us; speedup vs baseline: 5.0134x; 5.0134x over previous
//
#include <hip/hip_runtime.h>

#define NPOSTS 2048
#define SEQ 64
#define W2V 300
#define NH 5
#define HD 60
#define S2VD 256
#define HIDD 256
#define NEDGE 2047

// ---------------- Stage 1a: Q = Emb0 @ Wq^T + bq  (2048x300, K=300) ----------------
__global__ __launch_bounds__(320) void k_q(
    const int* __restrict__ nodeText, const float* __restrict__ embed_w,
    const float* __restrict__ Wqkv, const float* __restrict__ bqkv,
    float* __restrict__ Qout)
{
    const int r0 = blockIdx.x * 16;
    const int tid = threadIdx.x;
    __shared__ float sE[16][W2V];
    // stage 16 rows of Emb0 (token 0 of each post), float4
    for (int i = tid; i < 16 * 75; i += 320) {
        int r = i / 75, c4 = (i % 75) * 4;
        int t = nodeText[(size_t)(r0 + r) * SEQ];
        const float4 v = *reinterpret_cast<const float4*>(embed_w + (size_t)t * W2V + c4);
        sE[r][c4] = v.x; sE[r][c4 + 1] = v.y; sE[r][c4 + 2] = v.z; sE[r][c4 + 3] = v.w;
    }
    __syncthreads();
    if (tid < W2V) {
        const float* wr = Wqkv + (size_t)tid * W2V;
        float acc[16];
        float b = bqkv[tid];
        #pragma unroll
        for (int r = 0; r < 16; ++r) acc[r] = b;
        for (int c = 0; c < W2V; ++c) {
            float wv = wr[c];
            #pragma unroll
            for (int r = 0; r < 16; ++r) acc[r] = fmaf(wv, sE[r][c], acc[r]);
        }
        #pragma unroll
        for (int r = 0; r < 16; ++r) Qout[(size_t)(r0 + r) * W2V + tid] = acc[r];
    }
}

// ---------------- Stage 1b: u[p,h,:] = Q[p,h]_60 @ Wk_h  (K=60, coalesced W) ----------------
__global__ __launch_bounds__(320) void k_u(
    const float* __restrict__ Q, const float* __restrict__ Wqkv, float* __restrict__ uout)
{
    const int r0 = blockIdx.x * 16;
    const int h = blockIdx.y;
    const int tid = threadIdx.x;
    __shared__ float sQ[16][HD];
    for (int i = tid; i < 16 * HD; i += 320) {
        int r = i / HD, d = i % HD;
        sQ[r][d] = Q[(size_t)(r0 + r) * W2V + h * HD + d];
    }
    __syncthreads();
    if (tid < W2V) {
        float acc[16];
        #pragma unroll
        for (int r = 0; r < 16; ++r) acc[r] = 0.f;
        const float* wb = Wqkv + (size_t)(W2V + h * HD) * W2V + tid;
        for (int d = 0; d < HD; ++d) {
            float wv = wb[(size_t)d * W2V];
            #pragma unroll
            for (int r = 0; r < 16; ++r) acc[r] = fmaf(wv, sQ[r][d], acc[r]);
        }
        #pragma unroll
        for (int r = 0; r < 16; ++r)
            uout[(size_t)(r0 + r) * (NH * W2V) + h * W2V + tid] = acc[r];
    }
}

// ---------------- Stage 1c: per-post scores + softmax + e (writes e over u) ----------------
__global__ __launch_bounds__(256) void k_att(
    const int* __restrict__ nodeText, const float* __restrict__ embed_w,
    float* __restrict__ ue)   // in: u (2048x1500), out: e (same buffer, same rows)
{
    __shared__ float sEmb[SEQ][W2V + 1];  // stride 301 -> conflict-light
    __shared__ int   stoks[SEQ];
    __shared__ float ssc[NH * SEQ];

    const int p = blockIdx.x;
    const int tid = threadIdx.x;

    if (tid < SEQ) stoks[tid] = nodeText[p * SEQ + tid];
    __syncthreads();

    for (int idx = tid; idx < SEQ * 75; idx += 256) {
        int r = idx / 75, c4 = (idx % 75) * 4;
        const float4 v = *reinterpret_cast<const float4*>(embed_w + (size_t)stoks[r] * W2V + c4);
        float* dst = &sEmb[r][c4];
        dst[0] = v.x; dst[1] = v.y; dst[2] = v.z; dst[3] = v.w;
    }
    __syncthreads();

    // scores[h][j] = (u_h . Emb[j]) / sqrt(60); u read from global (L1-reused 64x)
    const float* urow = ue + (size_t)p * (NH * W2V);
    for (int i = tid; i < NH * SEQ; i += 256) {
        int h = i / SEQ, j = i % SEQ;
        const float4* u4 = reinterpret_cast<const float4*>(urow + h * W2V);
        const float* er = sEmb[j];
        float acc = 0.f;
        for (int c4 = 0; c4 < 75; ++c4) {
            float4 u = u4[c4];
            int c = c4 * 4;
            acc = fmaf(u.x, er[c], acc);
            acc = fmaf(u.y, er[c + 1], acc);
            acc = fmaf(u.z, er[c + 2], acc);
            acc = fmaf(u.w, er[c + 3], acc);
        }
        ssc[i] = acc * 0.12909944487358056f;  // 60^-0.5
    }
    __syncthreads();

    // wave-parallel softmax: waves 0..3 take heads 0..3, wave 0 takes head 4
    {
        const int wave = tid >> 6, lane = tid & 63;
        for (int h = wave; h < NH; h += 4) {
            float v = ssc[h * SEQ + lane];
            float m = v;
            #pragma unroll
            for (int off = 32; off > 0; off >>= 1) m = fmaxf(m, __shfl_xor(m, off));
            float e = expf(v - m);
            float s = e;
            #pragma unroll
            for (int off = 32; off > 0; off >>= 1) s += __shfl_xor(s, off);
            ssc[h * SEQ + lane] = e / s;
        }
    }
    __syncthreads();

    // e[h,c] = sum_j att[h,j] * Emb[j][c]; overwrite u row (only this block touches row p)
    float* erow = ue + (size_t)p * (NH * W2V);
    for (int i = tid; i < NH * W2V; i += 256) {
        int h = i / W2V, c = i % W2V;
        const float* att = ssc + h * SEQ;
        float acc = 0.f;
        #pragma unroll 4
        for (int j = 0; j < SEQ; ++j) acc = fmaf(att[j], sEmb[j][c], acc);
        erow[i] = acc;
    }
}

// ---------------- Stage 1d: fused o = Wv@e+bv ; mha = Wo@o+bo ; s2v = tanh(Ws@mha+bs) ----------------
__global__ __launch_bounds__(320) void k_oms(
    const float* __restrict__ e, const float* __restrict__ Wqkv, const float* __restrict__ bqkv,
    const float* __restrict__ Wo, const float* __restrict__ bo,
    const float* __restrict__ Ws, const float* __restrict__ bs,
    float* __restrict__ s2v_out)
{
    const int r0 = blockIdx.x * 8;
    const int tid = threadIdx.x;
    __shared__ float se[8][NH * W2V];   // 48000 B
    __shared__ float so[8][W2V];        // 9600 B
    __shared__ float sm[8][W2V];        // 9600 B

    for (int i = tid; i < 8 * 375; i += 320) {
        int r = i / 375, c4 = (i % 375) * 4;
        const float4 v = *reinterpret_cast<const float4*>(e + (size_t)(r0 + r) * (NH * W2V) + c4);
        float* dst = &se[r][c4];
        dst[0] = v.x; dst[1] = v.y; dst[2] = v.z; dst[3] = v.w;
    }
    __syncthreads();

    // o = Wv @ e_h + bv
    if (tid < W2V) {
        const int h = tid / HD;
        const float* wr = Wqkv + (size_t)(2 * W2V + tid) * W2V;
        float acc[8];
        float b = bqkv[2 * W2V + tid];
        #pragma unroll
        for (int r = 0; r < 8; ++r) acc[r] = b;
        for (int c = 0; c < W2V; ++c) {
            float wv = wr[c];
            #pragma unroll
            for (int r = 0; r < 8; ++r) acc[r] = fmaf(wv, se[r][h * W2V + c], acc[r]);
        }
        #pragma unroll
        for (int r = 0; r < 8; ++r) so[r][tid] = acc[r];
    }
    __syncthreads();

    // mha = Wo @ o + bo
    if (tid < W2V) {
        const float* wr = Wo + (size_t)tid * W2V;
        float acc[8];
        float b = bo[tid];
        #pragma unroll
        for (int r = 0; r < 8; ++r) acc[r] = b;
        for (int c = 0; c < W2V; ++c) {
            float wv = wr[c];
            #pragma unroll
            for (int r = 0; r < 8; ++r) acc[r] = fmaf(wv, so[r][c], acc[r]);
        }
        #pragma unroll
        for (int r = 0; r < 8; ++r) sm[r][tid] = acc[r];
    }
    __syncthreads();

    // s2v = tanh(Ws @ mha + bs)
    if (tid < S2VD) {
        const float* wr = Ws + (size_t)tid * W2V;
        float acc[8];
        float b = bs[tid];
        #pragma unroll
        for (int r = 0; r < 8; ++r) acc[r] = b;
        for (int c = 0; c < W2V; ++c) {
            float wv = wr[c];
            #pragma unroll
            for (int r = 0; r < 8; ++r) acc[r] = fmaf(wv, sm[r][c], acc[r]);
        }
        #pragma unroll
        for (int r = 0; r < 8; ++r)
            s2v_out[(size_t)(r0 + r) * S2VD + tid] = tanhf(acc[r]);
    }
}

// ---------------- Stage 2: GCN branches (blockIdx.y = branch: 0=TD, 1=BU) ----------------

__global__ __launch_bounds__(256) void k_deg(
    const int* __restrict__ eiTD, const int* __restrict__ eiBU, int* __restrict__ deg)
{
    const int b = blockIdx.y;
    const int* ei = b ? eiBU : eiTD;
    int e = blockIdx.x * 256 + threadIdx.x;
    if (e < NEDGE) atomicAdd(&deg[b * NPOSTS + ei[NEDGE + e]], 1);
}

__global__ __launch_bounds__(256) void k_gemm1(
    const float* __restrict__ x, const float* __restrict__ wtd, const float* __restrict__ wbu,
    float* __restrict__ hout)
{
    const int b = blockIdx.y;
    const float* w = b ? wbu : wtd;
    float* outp = hout + (size_t)b * NPOSTS * HIDD;
    const int r0 = blockIdx.x * 16;
    const int tid = threadIdx.x;
    __shared__ float sx[16][S2VD];
    for (int i = tid; i < 16 * S2VD; i += 256)
        sx[i / S2VD][i % S2VD] = x[(size_t)(r0 + i / S2VD) * S2VD + (i % S2VD)];
    __syncthreads();
    float acc[16];
    #pragma unroll
    for (int r = 0; r < 16; ++r) acc[r] = 0.f;
    const float* wr = w + (size_t)tid * S2VD;
    for (int c = 0; c < S2VD; ++c) {
        float wv = wr[c];
        #pragma unroll
        for (int r = 0; r < 16; ++r) acc[r] = fmaf(wv, sx[r][c], acc[r]);
    }
    #pragma unroll
    for (int r = 0; r < 16; ++r) outp[(size_t)(r0 + r) * HIDD + tid] = acc[r];
}

__global__ __launch_bounds__(256) void k_gemm2(
    const float* __restrict__ c1, const float* __restrict__ w2td, const float* __restrict__ w2bu,
    const float* __restrict__ rootv, float* __restrict__ hout)
{
    const int b = blockIdx.y;
    const float* w = b ? w2bu : w2td;
    const float* xin = c1 + (size_t)b * NPOSTS * HIDD;
    float* outp = hout + (size_t)b * NPOSTS * HIDD;
    const int r0 = blockIdx.x * 16;
    const int tid = threadIdx.x;
    __shared__ float sx[16][HIDD];
    for (int i = tid; i < 16 * HIDD; i += 256)
        sx[i / HIDD][i % HIDD] = fmaxf(xin[(size_t)(r0 + i / HIDD) * HIDD + (i % HIDD)], 0.f);
    __syncthreads();
    float acc[16];
    const float rv = rootv[b * HIDD + tid];
    #pragma unroll
    for (int r = 0; r < 16; ++r) acc[r] = rv;
    const float* wr = w + (size_t)tid * 512;
    for (int c = 0; c < HIDD; ++c) {
        float wv = wr[c];
        #pragma unroll
        for (int r = 0; r < 16; ++r) acc[r] = fmaf(wv, sx[r][c], acc[r]);
    }
    #pragma unroll
    for (int r = 0; r < 16; ++r) outp[(size_t)(r0 + r) * HIDD + tid] = acc[r];
}

__global__ __launch_bounds__(256) void k_init(
    const float* __restrict__ h, const float* __restrict__ btd, const float* __restrict__ bbu,
    const int* __restrict__ deg, float* __restrict__ cout_)
{
    const int b = blockIdx.y, n = blockIdx.x, tid = threadIdx.x;
    const float* bias = b ? bbu : btd;
    const float* hb = h + (size_t)b * NPOSTS * HIDD;
    float* cb = cout_ + (size_t)b * NPOSTS * HIDD;
    float dinv = 1.f / (float)(deg[b * NPOSTS + n] + 1);
    cb[(size_t)n * HIDD + tid] = bias[tid] + hb[(size_t)n * HIDD + tid] * dinv;
}

__global__ __launch_bounds__(256) void k_scat(
    const int* __restrict__ eiTD, const int* __restrict__ eiBU,
    const float* __restrict__ h, const int* __restrict__ deg, float* __restrict__ cacc)
{
    const int b = blockIdx.y, e = blockIdx.x, tid = threadIdx.x;
    const int* ei = b ? eiBU : eiTD;
    const int s = ei[e], d = ei[NEDGE + e];
    const int* dg = deg + b * NPOSTS;
    float norm = rsqrtf((float)(dg[s] + 1)) * rsqrtf((float)(dg[d] + 1));
    const float* hb = h + (size_t)b * NPOSTS * HIDD;
    float* cb = cacc + (size_t)b * NPOSTS * HIDD;
    atomicAdd(&cb[(size_t)d * HIDD + tid], norm * hb[(size_t)s * HIDD + tid]);
}

__global__ __launch_bounds__(256) void k_root(
    const float* __restrict__ s2v, const float* __restrict__ c1,
    const float* __restrict__ w2td, const float* __restrict__ w2bu,
    const int* __restrict__ rootPtr, float* __restrict__ rootv, float* __restrict__ c1root)
{
    const int b = blockIdx.y, tid = threadIdx.x;
    const float* w2 = b ? w2bu : w2td;
    const int root = rootPtr[0];
    __shared__ float sx[S2VD];
    sx[tid] = fmaxf(s2v[(size_t)root * S2VD + tid], 0.f);
    __syncthreads();
    const float* cb = c1 + (size_t)b * NPOSTS * HIDD;
    c1root[b * HIDD + tid] = cb[(size_t)root * HIDD + tid];
    const float* wr = w2 + (size_t)tid * 512 + 256;
    float acc = 0.f;
    #pragma unroll 4
    for (int c = 0; c < S2VD; ++c) acc = fmaf(wr[c], sx[c], acc);
    rootv[b * HIDD + tid] = acc;
}

__global__ __launch_bounds__(256) void k_reduce(
    const float* __restrict__ cacc, float* __restrict__ msum)
{
    const int b = blockIdx.y, tid = threadIdx.x;
    const int base = blockIdx.x * 32;
    const float* cb = cacc + (size_t)b * NPOSTS * HIDD;
    float local = 0.f;
    #pragma unroll 4
    for (int r = 0; r < 32; ++r) local += fmaxf(cb[(size_t)(base + r) * HIDD + tid], 0.f);
    atomicAdd(&msum[b * HIDD + tid], local);
}

__global__ __launch_bounds__(256) void k_final(
    const float* __restrict__ c1root, const float* __restrict__ msum,
    const float* __restrict__ fc_w, const float* __restrict__ fc_b, float* __restrict__ outp)
{
    const int tid = threadIdx.x;
    __shared__ float sf[1024];
    for (int k = tid; k < 1024; k += 256) {
        int seg = k >> 8, idx = k & 255;
        float v;
        if (seg == 0)      v = c1root[idx];
        else if (seg == 1) v = msum[idx] * (1.f / (float)NPOSTS);
        else if (seg == 2) v = c1root[256 + idx];
        else               v = msum[256 + idx] * (1.f / (float)NPOSTS);
        sf[k] = v;
    }
    __syncthreads();
    const int t = tid >> 6, lane = tid & 63;
    float part = 0.f;
    for (int k = lane; k < 1024; k += 64) part = fmaf(fc_w[t * 1024 + k], sf[k], part);
    #pragma unroll
    for (int off = 32; off > 0; off >>= 1) part += __shfl_down(part, off);
    if (lane == 0) outp[t] = part + fc_b[t];
}

extern "C" void kernel_launch(void* const* d_in, const int* in_sizes, int n_in,
                              void* d_out, int out_size, void* d_ws, size_t ws_size,
                              hipStream_t stream) {
    (void)in_sizes; (void)n_in; (void)out_size; (void)ws_size;

    const int*   nodeText   = (const int*)d_in[0];
    const int*   eiTD       = (const int*)d_in[1];
    const int*   eiBU       = (const int*)d_in[2];
    const int*   threadIdxP = (const int*)d_in[3];
    const float* embed_w    = (const float*)d_in[5];
    const float* in_proj_w  = (const float*)d_in[6];
    const float* in_proj_b  = (const float*)d_in[7];
    const float* out_proj_w = (const float*)d_in[8];
    const float* out_proj_b = (const float*)d_in[9];
    const float* s2v_w      = (const float*)d_in[10];
    const float* s2v_b      = (const float*)d_in[11];
    const float* td_w1      = (const float*)d_in[12];
    const float* td_b1      = (const float*)d_in[13];
    const float* td_w2      = (const float*)d_in[14];
    const float* td_b2      = (const float*)d_in[15];
    const float* bu_w1      = (const float*)d_in[16];
    const float* bu_b1      = (const float*)d_in[17];
    const float* bu_w2      = (const float*)d_in[18];
    const float* bu_b2      = (const float*)d_in[19];
    const float* fc_w       = (const float*)d_in[20];
    const float* fc_b       = (const float*)d_in[21];
    float* outp = (float*)d_out;

    // workspace layout
    char* w = (char*)d_ws;
    int*   deg    = (int*)w;                          // 16384 B
    float* msum   = (float*)(w + 16384);              // 2048 B
    float* rootv  = (float*)(w + 16384 + 2048);
    float* c1root = (float*)(w + 16384 + 4096);
    float* s2v    = (float*)(w + 24576);                              // 2 MB
    float* hbuf   = (float*)(w + 24576 + 2097152);                    // 2 MB x2 branches
    float* cbuf   = (float*)(w + 24576 + 2097152 + 4194304);          // 2 MB x2 branches
    float* Qbuf   = (float*)(w + 24576 + 2097152 + 4194304 + 4194304);            // 2.46 MB
    float* uebuf  = (float*)(w + 24576 + 2097152 + 4194304 + 4194304 + 2457600);  // 12.29 MB

    hipMemsetAsync(d_ws, 0, 16384 + 2048, stream);

    // ---- stage 1 ----
    k_q  <<<NPOSTS / 16, 320, 0, stream>>>(nodeText, embed_w, in_proj_w, in_proj_b, Qbuf);
    k_u  <<<dim3(NPOSTS / 16, NH), 320, 0, stream>>>(Qbuf, in_proj_w, uebuf);
    k_att<<<NPOSTS, 256, 0, stream>>>(nodeText, embed_w, uebuf);
    k_oms<<<NPOSTS / 8, 320, 0, stream>>>(uebuf, in_proj_w, in_proj_b,
                                          out_proj_w, out_proj_b, s2v_w, s2v_b, s2v);

    // ---- stage 2 ----
    k_deg<<<dim3((NEDGE + 255) / 256, 2), 256, 0, stream>>>(eiTD, eiBU, deg);

    k_gemm1<<<dim3(NPOSTS / 16, 2), 256, 0, stream>>>(s2v, td_w1, bu_w1, hbuf);
    k_init<<<dim3(NPOSTS, 2), 256, 0, stream>>>(hbuf, td_b1, bu_b1, deg, cbuf);
    k_scat<<<dim3(NEDGE, 2), 256, 0, stream>>>(eiTD, eiBU, hbuf, deg, cbuf);

    k_root<<<dim3(1, 2), 256, 0, stream>>>(s2v, cbuf, td_w2, bu_w2, threadIdxP, rootv, c1root);

    k_gemm2<<<dim3(NPOSTS / 16, 2), 256, 0, stream>>>(cbuf, td_w2, bu_w2, rootv, hbuf);
    k_init<<<dim3(NPOSTS, 2), 256, 0, stream>>>(hbuf, td_b2, bu_b2, deg, cbuf);
    k_scat<<<dim3(NEDGE, 2), 256, 0, stream>>>(eiTD, eiBU, hbuf, deg, cbuf);

    k_reduce<<<dim3(NPOSTS / 32, 2), 256, 0, stream>>>(cbuf, msum);

    k_final<<<1, 256, 0, stream>>>(c1root, msum, fc_w, fc_b, outp);
}

// Round 3
// 289.840 us; speedup vs baseline: 5.9730x; 1.1914x over previous
//
#include <hip/hip_runtime.h>

#define NPOSTS 2048
#define SEQ 64
#define W2V 300
#define NH 5
#define HD 60
#define S2VD 256
#define HIDD 256
#define NEDGE 2047
#define UDIM (NH * W2V)   // 1500

__device__ __forceinline__ float dot4(float4 a, float4 b) {
    return fmaf(a.x, b.x, fmaf(a.y, b.y, fmaf(a.z, b.z, a.w * b.w)));
}

// ---------------- Stage 1a: fused q = Wq@Emb0+bq ; u_h = Wk_h^T q_h  (4 posts/block) ----------------
__global__ __launch_bounds__(320) void k_qu(
    const int* __restrict__ nodeText, const float* __restrict__ embed_w,
    const float* __restrict__ Wqkv, const float* __restrict__ bqkv,
    float* __restrict__ uout)
{
    const int r0 = blockIdx.x * 4;
    const int tid = threadIdx.x;
    __shared__ float sE[4][W2V];
    __shared__ float sQ[4][W2V];

    if (tid < 300) {
        int r = tid / 75, c4 = (tid % 75) * 4;
        int t = nodeText[(size_t)(r0 + r) * SEQ];
        const float4 v = *reinterpret_cast<const float4*>(embed_w + (size_t)t * W2V + c4);
        sE[r][c4] = v.x; sE[r][c4 + 1] = v.y; sE[r][c4 + 2] = v.z; sE[r][c4 + 3] = v.w;
    }
    __syncthreads();

    if (tid < W2V) {
        const float* wr = Wqkv + (size_t)tid * W2V;
        float b = bqkv[tid];
        float a0 = b, a1 = b, a2 = b, a3 = b;
        for (int c = 0; c < W2V; ++c) {
            float wv = wr[c];
            a0 = fmaf(wv, sE[0][c], a0);
            a1 = fmaf(wv, sE[1][c], a1);
            a2 = fmaf(wv, sE[2][c], a2);
            a3 = fmaf(wv, sE[3][c], a3);
        }
        sQ[0][tid] = a0; sQ[1][tid] = a1; sQ[2][tid] = a2; sQ[3][tid] = a3;
    }
    __syncthreads();

    if (tid < W2V) {
        for (int h = 0; h < NH; ++h) {
            const float* wb = Wqkv + (size_t)(W2V + h * HD) * W2V + tid;  // lane-coalesced
            const float* q0 = &sQ[0][h * HD];
            const float* q1 = &sQ[1][h * HD];
            const float* q2 = &sQ[2][h * HD];
            const float* q3 = &sQ[3][h * HD];
            float a0 = 0.f, a1 = 0.f, a2 = 0.f, a3 = 0.f;
            for (int d = 0; d < HD; ++d) {
                float wv = wb[(size_t)d * W2V];
                a0 = fmaf(wv, q0[d], a0);
                a1 = fmaf(wv, q1[d], a1);
                a2 = fmaf(wv, q2[d], a2);
                a3 = fmaf(wv, q3[d], a3);
            }
            uout[(size_t)(r0 + 0) * UDIM + h * W2V + tid] = a0;
            uout[(size_t)(r0 + 1) * UDIM + h * W2V + tid] = a1;
            uout[(size_t)(r0 + 2) * UDIM + h * W2V + tid] = a2;
            uout[(size_t)(r0 + 3) * UDIM + h * W2V + tid] = a3;
        }
    }
}

// ---------------- Stage 1b: per-post scores + softmax + e (overwrites u row) ----------------
__global__ __launch_bounds__(320) void k_att(
    const int* __restrict__ nodeText, const float* __restrict__ embed_w,
    float* __restrict__ ue)
{
    __shared__ int   stoks[SEQ];
    __shared__ float ssc[NH * SEQ];
    __shared__ float part[4][75][21];   // stride 21 (gcd(21,32)=1) -> conflict-free

    const int p = blockIdx.x;
    const int tid = threadIdx.x;
    const int wave = tid >> 6, lane = tid & 63;

    if (tid < SEQ) stoks[tid] = nodeText[p * SEQ + tid];
    __syncthreads();

    // --- load u into registers (coalesced float4; each wave holds full u) ---
    const float4* su4 = reinterpret_cast<const float4*>(ue + (size_t)p * UDIM);
    float4 u00 = su4[0 * 75 + lane];
    float4 u01 = su4[1 * 75 + lane];
    float4 u02 = su4[2 * 75 + lane];
    float4 u03 = su4[3 * 75 + lane];
    float4 u04 = su4[4 * 75 + lane];
    float4 z = make_float4(0.f, 0.f, 0.f, 0.f);
    float4 u10 = z, u11 = z, u12 = z, u13 = z, u14 = z;
    if (lane < 11) {
        u10 = su4[0 * 75 + 64 + lane];
        u11 = su4[1 * 75 + 64 + lane];
        u12 = su4[2 * 75 + 64 + lane];
        u13 = su4[3 * 75 + 64 + lane];
        u14 = su4[4 * 75 + 64 + lane];
    }

    // --- scores: wave-cooperative token dots; wave w owns tokens w, w+5, ... ---
    const float SC = 0.12909944487358056f;  // 60^-0.5
    for (int j = wave; j < SEQ; j += 5) {
        const float4* er = reinterpret_cast<const float4*>(embed_w + (size_t)stoks[j] * W2V);
        const float4 a = er[lane];
        float4 bb = z;
        if (lane < 11) bb = er[64 + lane];
        float s0 = dot4(a, u00) + dot4(bb, u10);
        float s1 = dot4(a, u01) + dot4(bb, u11);
        float s2 = dot4(a, u02) + dot4(bb, u12);
        float s3 = dot4(a, u03) + dot4(bb, u13);
        float s4 = dot4(a, u04) + dot4(bb, u14);
        #pragma unroll
        for (int off = 32; off > 0; off >>= 1) {
            s0 += __shfl_xor(s0, off);
            s1 += __shfl_xor(s1, off);
            s2 += __shfl_xor(s2, off);
            s3 += __shfl_xor(s3, off);
            s4 += __shfl_xor(s4, off);
        }
        if (lane == 0) {
            ssc[0 * SEQ + j] = s0 * SC;
            ssc[1 * SEQ + j] = s1 * SC;
            ssc[2 * SEQ + j] = s2 * SC;
            ssc[3 * SEQ + j] = s3 * SC;
            ssc[4 * SEQ + j] = s4 * SC;
        }
    }
    __syncthreads();

    // --- softmax: wave w handles head w (5 waves, 5 heads) ---
    {
        float v = ssc[wave * SEQ + lane];
        float m = v;
        #pragma unroll
        for (int off = 32; off > 0; off >>= 1) m = fmaxf(m, __shfl_xor(m, off));
        float e = expf(v - m);
        float s = e;
        #pragma unroll
        for (int off = 32; off > 0; off >>= 1) s += __shfl_xor(s, off);
        ssc[wave * SEQ + lane] = e / s;
    }
    __syncthreads();

    // --- e[h,c] = sum_j att[h,j]*Emb[j][c]; c-major threads, 4-way j split ---
    if (tid < 300) {
        const int c4 = tid % 75, g = tid / 75;
        float4 a0 = z, a1 = z, a2 = z, a3 = z, a4 = z;
        for (int jj = 0; jj < 16; ++jj) {
            int j = g * 16 + jj;
            const float4 em = *reinterpret_cast<const float4*>(
                embed_w + (size_t)stoks[j] * W2V + c4 * 4);
            float w0 = ssc[0 * SEQ + j], w1 = ssc[1 * SEQ + j], w2 = ssc[2 * SEQ + j];
            float w3 = ssc[3 * SEQ + j], w4 = ssc[4 * SEQ + j];
            a0.x = fmaf(w0, em.x, a0.x); a0.y = fmaf(w0, em.y, a0.y); a0.z = fmaf(w0, em.z, a0.z); a0.w = fmaf(w0, em.w, a0.w);
            a1.x = fmaf(w1, em.x, a1.x); a1.y = fmaf(w1, em.y, a1.y); a1.z = fmaf(w1, em.z, a1.z); a1.w = fmaf(w1, em.w, a1.w);
            a2.x = fmaf(w2, em.x, a2.x); a2.y = fmaf(w2, em.y, a2.y); a2.z = fmaf(w2, em.z, a2.z); a2.w = fmaf(w2, em.w, a2.w);
            a3.x = fmaf(w3, em.x, a3.x); a3.y = fmaf(w3, em.y, a3.y); a3.z = fmaf(w3, em.z, a3.z); a3.w = fmaf(w3, em.w, a3.w);
            a4.x = fmaf(w4, em.x, a4.x); a4.y = fmaf(w4, em.y, a4.y); a4.z = fmaf(w4, em.z, a4.z); a4.w = fmaf(w4, em.w, a4.w);
        }
        float* pp = &part[g][c4][0];
        pp[0] = a0.x; pp[1] = a0.y; pp[2] = a0.z; pp[3] = a0.w;
        pp[4] = a1.x; pp[5] = a1.y; pp[6] = a1.z; pp[7] = a1.w;
        pp[8] = a2.x; pp[9] = a2.y; pp[10] = a2.z; pp[11] = a2.w;
        pp[12] = a3.x; pp[13] = a3.y; pp[14] = a3.z; pp[15] = a3.w;
        pp[16] = a4.x; pp[17] = a4.y; pp[18] = a4.z; pp[19] = a4.w;
    }
    __syncthreads();

    float4* eo = reinterpret_cast<float4*>(ue + (size_t)p * UDIM);
    for (int o = tid; o < 375; o += 320) {
        int h = o / 75, c4 = o % 75;
        float x = 0.f, y = 0.f, zz = 0.f, w = 0.f;
        #pragma unroll
        for (int g = 0; g < 4; ++g) {
            const float* pp = &part[g][c4][h * 4];
            x += pp[0]; y += pp[1]; zz += pp[2]; w += pp[3];
        }
        eo[o] = make_float4(x, y, zz, w);
    }
}

// ---------------- Stage 1c: fused o = Wv@e+bv ; mha = Wo@o+bo ; s2v = tanh(Ws@mha+bs) ----------------
__global__ __launch_bounds__(320) void k_oms(
    const float* __restrict__ e, const float* __restrict__ Wqkv, const float* __restrict__ bqkv,
    const float* __restrict__ Wo, const float* __restrict__ bo,
    const float* __restrict__ Ws, const float* __restrict__ bs,
    float* __restrict__ s2v_out)
{
    const int r0 = blockIdx.x * 4;
    const int tid = threadIdx.x;
    __shared__ float se[4][UDIM];   // 24 KB
    __shared__ float so[4][W2V];
    __shared__ float sm[4][W2V];

    for (int i = tid; i < 4 * 375; i += 320) {
        int r = i / 375, c4 = (i % 375) * 4;
        const float4 v = *reinterpret_cast<const float4*>(e + (size_t)(r0 + r) * UDIM + c4);
        se[r][c4] = v.x; se[r][c4 + 1] = v.y; se[r][c4 + 2] = v.z; se[r][c4 + 3] = v.w;
    }
    __syncthreads();

    if (tid < W2V) {
        const int h = tid / HD;
        const float* wr = Wqkv + (size_t)(2 * W2V + tid) * W2V;
        float b = bqkv[2 * W2V + tid];
        float a0 = b, a1 = b, a2 = b, a3 = b;
        const float* e0 = &se[0][h * W2V];
        const float* e1 = &se[1][h * W2V];
        const float* e2 = &se[2][h * W2V];
        const float* e3 = &se[3][h * W2V];
        for (int c = 0; c < W2V; ++c) {
            float wv = wr[c];
            a0 = fmaf(wv, e0[c], a0);
            a1 = fmaf(wv, e1[c], a1);
            a2 = fmaf(wv, e2[c], a2);
            a3 = fmaf(wv, e3[c], a3);
        }
        so[0][tid] = a0; so[1][tid] = a1; so[2][tid] = a2; so[3][tid] = a3;
    }
    __syncthreads();

    if (tid < W2V) {
        const float* wr = Wo + (size_t)tid * W2V;
        float b = bo[tid];
        float a0 = b, a1 = b, a2 = b, a3 = b;
        for (int c = 0; c < W2V; ++c) {
            float wv = wr[c];
            a0 = fmaf(wv, so[0][c], a0);
            a1 = fmaf(wv, so[1][c], a1);
            a2 = fmaf(wv, so[2][c], a2);
            a3 = fmaf(wv, so[3][c], a3);
        }
        sm[0][tid] = a0; sm[1][tid] = a1; sm[2][tid] = a2; sm[3][tid] = a3;
    }
    __syncthreads();

    if (tid < S2VD) {
        const float* wr = Ws + (size_t)tid * W2V;
        float b = bs[tid];
        float a0 = b, a1 = b, a2 = b, a3 = b;
        for (int c = 0; c < W2V; ++c) {
            float wv = wr[c];
            a0 = fmaf(wv, sm[0][c], a0);
            a1 = fmaf(wv, sm[1][c], a1);
            a2 = fmaf(wv, sm[2][c], a2);
            a3 = fmaf(wv, sm[3][c], a3);
        }
        s2v_out[(size_t)(r0 + 0) * S2VD + tid] = tanhf(a0);
        s2v_out[(size_t)(r0 + 1) * S2VD + tid] = tanhf(a1);
        s2v_out[(size_t)(r0 + 2) * S2VD + tid] = tanhf(a2);
        s2v_out[(size_t)(r0 + 3) * S2VD + tid] = tanhf(a3);
    }
}

// ---------------- Stage 2: GCN branches (blockIdx.y = branch: 0=TD, 1=BU) ----------------

__global__ __launch_bounds__(256) void k_deg(
    const int* __restrict__ eiTD, const int* __restrict__ eiBU, int* __restrict__ deg)
{
    const int b = blockIdx.y;
    const int* ei = b ? eiBU : eiTD;
    int e = blockIdx.x * 256 + threadIdx.x;
    if (e < NEDGE) atomicAdd(&deg[b * NPOSTS + ei[NEDGE + e]], 1);
}

// h = x @ w.T ; c = bias + h*dinv (fused self-loop init)
__global__ __launch_bounds__(256) void k_gemm1(
    const float* __restrict__ x, const float* __restrict__ wtd, const float* __restrict__ wbu,
    const float* __restrict__ btd, const float* __restrict__ bbu, const int* __restrict__ deg,
    float* __restrict__ hout, float* __restrict__ cout_)
{
    const int b = blockIdx.y;
    const float* w = b ? wbu : wtd;
    const float* bias = b ? bbu : btd;
    float* hb = hout + (size_t)b * NPOSTS * HIDD;
    float* cb = cout_ + (size_t)b * NPOSTS * HIDD;
    const int* dg = deg + b * NPOSTS;
    const int r0 = blockIdx.x * 16;
    const int tid = threadIdx.x;
    __shared__ float sx[16][S2VD];
    for (int i = tid; i < 16 * S2VD; i += 256)
        sx[i / S2VD][i % S2VD] = x[(size_t)(r0 + i / S2VD) * S2VD + (i % S2VD)];
    __syncthreads();
    float acc[16];
    #pragma unroll
    for (int r = 0; r < 16; ++r) acc[r] = 0.f;
    const float* wr = w + (size_t)tid * S2VD;
    for (int c = 0; c < S2VD; ++c) {
        float wv = wr[c];
        #pragma unroll
        for (int r = 0; r < 16; ++r) acc[r] = fmaf(wv, sx[r][c], acc[r]);
    }
    float bv = bias[tid];
    #pragma unroll
    for (int r = 0; r < 16; ++r) {
        int n = r0 + r;
        float dinv = 1.f / (float)(dg[n] + 1);
        hb[(size_t)n * HIDD + tid] = acc[r];
        cb[(size_t)n * HIDD + tid] = bv + acc[r] * dinv;
    }
}

// h2 = relu(c1) @ w2[:, :256].T + rootvec ; c2 = bias2 + h2*dinv (fused)
__global__ __launch_bounds__(256) void k_gemm2(
    const float* __restrict__ c1, const float* __restrict__ w2td, const float* __restrict__ w2bu,
    const float* __restrict__ btd, const float* __restrict__ bbu, const int* __restrict__ deg,
    const float* __restrict__ rootv, float* __restrict__ hout, float* __restrict__ cout_)
{
    const int b = blockIdx.y;
    const float* w = b ? w2bu : w2td;
    const float* bias = b ? bbu : btd;
    const float* xin = c1 + (size_t)b * NPOSTS * HIDD;
    float* hb = hout + (size_t)b * NPOSTS * HIDD;
    float* cb = cout_ + (size_t)b * NPOSTS * HIDD;
    const int* dg = deg + b * NPOSTS;
    const int r0 = blockIdx.x * 16;
    const int tid = threadIdx.x;
    __shared__ float sx[16][HIDD];
    for (int i = tid; i < 16 * HIDD; i += 256)
        sx[i / HIDD][i % HIDD] = fmaxf(xin[(size_t)(r0 + i / HIDD) * HIDD + (i % HIDD)], 0.f);
    __syncthreads();
    float acc[16];
    const float rv = rootv[b * HIDD + tid];
    #pragma unroll
    for (int r = 0; r < 16; ++r) acc[r] = rv;
    const float* wr = w + (size_t)tid * 512;
    for (int c = 0; c < HIDD; ++c) {
        float wv = wr[c];
        #pragma unroll
        for (int r = 0; r < 16; ++r) acc[r] = fmaf(wv, sx[r][c], acc[r]);
    }
    float bv = bias[tid];
    #pragma unroll
    for (int r = 0; r < 16; ++r) {
        int n = r0 + r;
        float dinv = 1.f / (float)(dg[n] + 1);
        hb[(size_t)n * HIDD + tid] = acc[r];
        cb[(size_t)n * HIDD + tid] = bv + acc[r] * dinv;
    }
}

__global__ __launch_bounds__(256) void k_scat(
    const int* __restrict__ eiTD, const int* __restrict__ eiBU,
    const float* __restrict__ h, const int* __restrict__ deg, float* __restrict__ cacc)
{
    const int b = blockIdx.y, e = blockIdx.x, tid = threadIdx.x;
    const int* ei = b ? eiBU : eiTD;
    const int s = ei[e], d = ei[NEDGE + e];
    const int* dg = deg + b * NPOSTS;
    float norm = rsqrtf((float)(dg[s] + 1)) * rsqrtf((float)(dg[d] + 1));
    const float* hb = h + (size_t)b * NPOSTS * HIDD;
    float* cb = cacc + (size_t)b * NPOSTS * HIDD;
    atomicAdd(&cb[(size_t)d * HIDD + tid], norm * hb[(size_t)s * HIDD + tid]);
}

__global__ __launch_bounds__(256) void k_root(
    const float* __restrict__ s2v, const float* __restrict__ c1,
    const float* __restrict__ w2td, const float* __restrict__ w2bu,
    const int* __restrict__ rootPtr, float* __restrict__ rootv, float* __restrict__ c1root)
{
    const int b = blockIdx.y, tid = threadIdx.x;
    const float* w2 = b ? w2bu : w2td;
    const int root = rootPtr[0];
    __shared__ float sx[S2VD];
    sx[tid] = fmaxf(s2v[(size_t)root * S2VD + tid], 0.f);
    __syncthreads();
    const float* cb = c1 + (size_t)b * NPOSTS * HIDD;
    c1root[b * HIDD + tid] = cb[(size_t)root * HIDD + tid];
    const float* wr = w2 + (size_t)tid * 512 + 256;
    float acc = 0.f;
    #pragma unroll 4
    for (int c = 0; c < S2VD; ++c) acc = fmaf(wr[c], sx[c], acc);
    rootv[b * HIDD + tid] = acc;
}

__global__ __launch_bounds__(256) void k_reduce(
    const float* __restrict__ cacc, float* __restrict__ msum)
{
    const int b = blockIdx.y, tid = threadIdx.x;
    const int base = blockIdx.x * 32;
    const float* cb = cacc + (size_t)b * NPOSTS * HIDD;
    float local = 0.f;
    #pragma unroll 4
    for (int r = 0; r < 32; ++r) local += fmaxf(cb[(size_t)(base + r) * HIDD + tid], 0.f);
    atomicAdd(&msum[b * HIDD + tid], local);
}

__global__ __launch_bounds__(256) void k_final(
    const float* __restrict__ c1root, const float* __restrict__ msum,
    const float* __restrict__ fc_w, const float* __restrict__ fc_b, float* __restrict__ outp)
{
    const int tid = threadIdx.x;
    __shared__ float sf[1024];
    for (int k = tid; k < 1024; k += 256) {
        int seg = k >> 8, idx = k & 255;
        float v;
        if (seg == 0)      v = c1root[idx];
        else if (seg == 1) v = msum[idx] * (1.f / (float)NPOSTS);
        else if (seg == 2) v = c1root[256 + idx];
        else               v = msum[256 + idx] * (1.f / (float)NPOSTS);
        sf[k] = v;
    }
    __syncthreads();
    const int t = tid >> 6, lane = tid & 63;
    float part = 0.f;
    for (int k = lane; k < 1024; k += 64) part = fmaf(fc_w[t * 1024 + k], sf[k], part);
    #pragma unroll
    for (int off = 32; off > 0; off >>= 1) part += __shfl_down(part, off);
    if (lane == 0) outp[t] = part + fc_b[t];
}

extern "C" void kernel_launch(void* const* d_in, const int* in_sizes, int n_in,
                              void* d_out, int out_size, void* d_ws, size_t ws_size,
                              hipStream_t stream) {
    (void)in_sizes; (void)n_in; (void)out_size; (void)ws_size;

    const int*   nodeText   = (const int*)d_in[0];
    const int*   eiTD       = (const int*)d_in[1];
    const int*   eiBU       = (const int*)d_in[2];
    const int*   threadIdxP = (const int*)d_in[3];
    const float* embed_w    = (const float*)d_in[5];
    const float* in_proj_w  = (const float*)d_in[6];
    const float* in_proj_b  = (const float*)d_in[7];
    const float* out_proj_w = (const float*)d_in[8];
    const float* out_proj_b = (const float*)d_in[9];
    const float* s2v_w      = (const float*)d_in[10];
    const float* s2v_b      = (const float*)d_in[11];
    const float* td_w1      = (const float*)d_in[12];
    const float* td_b1      = (const float*)d_in[13];
    const float* td_w2      = (const float*)d_in[14];
    const float* td_b2      = (const float*)d_in[15];
    const float* bu_w1      = (const float*)d_in[16];
    const float* bu_b1      = (const float*)d_in[17];
    const float* bu_w2      = (const float*)d_in[18];
    const float* bu_b2      = (const float*)d_in[19];
    const float* fc_w       = (const float*)d_in[20];
    const float* fc_b       = (const float*)d_in[21];
    float* outp = (float*)d_out;

    // workspace layout
    char* w = (char*)d_ws;
    int*   deg    = (int*)w;                          // 16384 B
    float* msum   = (float*)(w + 16384);              // 2048 B
    float* rootv  = (float*)(w + 16384 + 2048);
    float* c1root = (float*)(w + 16384 + 4096);
    float* s2v    = (float*)(w + 24576);                              // 2 MB
    float* hbuf   = (float*)(w + 24576 + 2097152);                    // 4 MB (2 branches)
    float* cbuf   = (float*)(w + 24576 + 2097152 + 4194304);          // 4 MB (2 branches)
    float* uebuf  = (float*)(w + 24576 + 2097152 + 4194304 + 4194304); // 12.29 MB (u then e)

    hipMemsetAsync(d_ws, 0, 16384 + 2048, stream);

    // ---- stage 2 prep (independent of stage 1) ----
    k_deg<<<dim3((NEDGE + 255) / 256, 2), 256, 0, stream>>>(eiTD, eiBU, deg);

    // ---- stage 1 ----
    k_qu <<<NPOSTS / 4, 320, 0, stream>>>(nodeText, embed_w, in_proj_w, in_proj_b, uebuf);
    k_att<<<NPOSTS, 320, 0, stream>>>(nodeText, embed_w, uebuf);
    k_oms<<<NPOSTS / 4, 320, 0, stream>>>(uebuf, in_proj_w, in_proj_b,
                                          out_proj_w, out_proj_b, s2v_w, s2v_b, s2v);

    // ---- stage 2 ----
    k_gemm1<<<dim3(NPOSTS / 16, 2), 256, 0, stream>>>(s2v, td_w1, bu_w1, td_b1, bu_b1, deg,
                                                      hbuf, cbuf);
    k_scat<<<dim3(NEDGE, 2), 256, 0, stream>>>(eiTD, eiBU, hbuf, deg, cbuf);

    k_root<<<dim3(1, 2), 256, 0, stream>>>(s2v, cbuf, td_w2, bu_w2, threadIdxP, rootv, c1root);

    k_gemm2<<<dim3(NPOSTS / 16, 2), 256, 0, stream>>>(cbuf, td_w2, bu_w2, td_b2, bu_b2, deg,
                                                      rootv, hbuf, cbuf);
    k_scat<<<dim3(NEDGE, 2), 256, 0, stream>>>(eiTD, eiBU, hbuf, deg, cbuf);

    k_reduce<<<dim3(NPOSTS / 32, 2), 256, 0, stream>>>(cbuf, msum);

    k_final<<<1, 256, 0, stream>>>(c1root, msum, fc_w, fc_b, outp);
}